// Round 23
// baseline (89.106 us; speedup 1.0000x reference)
//
#include <hip/hip_runtime.h>

// Event-to-image: B=16, N=500000 events (t,x,y,p) f32 -> (16,720,1280,3) f32.
// Last-event-wins per pixel: p==1 -> (0,255,255); p==0 -> (255,0,255);
// untouched -> (255,255,510). Order-independent via max over
// key = ((event_idx+1)<<1)|p (20 bits), pk = x<<20 | key (x = 11 bits,
// 1-ROW bands: 720 bins/batch).
//
// R23: render block granularity probe (last un-probed axis; 7 prior render
// micro-surgeries all null at 80+-3). 128-thread (2-wave) render blocks on
// 1-row bands: barriers sync 2 waves (near-free), 16 independent blocks/CU
// (vs 8) at the SAME 32 waves/CU, per-phase LDS bursts quartered. Scatter:
// R22 structure at 720 row bins (37.7KB LDS -> 4x512 = 2048 thr/CU kept).

#define WIDTH   1280
#define HEIGHT  720
#define BATCH   16
#define NEV     500000
#define THREADS 512                         // scatter block
#define EPT     16
#define EVPB    (THREADS * EPT)             // 8192 events per block
#define BPB     ((NEV + EVPB - 1) / EVPB)   // 62 blocks per batch
#define NBLK    (BATCH * BPB)               // 992
#define NROWS   720                         // 1-row bins per batch
#define PH      (NROWS + 1)                 // 721 prefix entries per block
#define RTHREADS 128                        // render block (2 waves)
#define STCAP   1024                        // staged cap (lambda=694 +12.5sig)

typedef float f4 __attribute__((ext_vector_type(4)));
typedef const __attribute__((address_space(1))) unsigned int GU;
typedef __attribute__((address_space(3))) unsigned int LU;

// ws layout: [0, NBLK*PH*4)=pref_g (2.86 MB); [0x400000, +NBLK*EVPB*4)=bins (32.5 MB)

__global__ __launch_bounds__(THREADS, 8) void scatter_k(const float4* __restrict__ ev,
                                                        unsigned int* __restrict__ pref_g,
                                                        unsigned int* __restrict__ bins) {
    __shared__ unsigned int hist[NROWS];
    __shared__ unsigned int offs[NROWS];
    __shared__ unsigned int wtot[8];
    __shared__ unsigned int stage[EVPB];     // 32 KB; total 37.7 KB -> 4 blocks/CU

    int t = threadIdx.x;
    int batch = blockIdx.x / BPB;
    int blk   = blockIdx.x % BPB;
    int ev0   = blk * EVPB;
    int cnt   = NEV - ev0; if (cnt > EVPB) cnt = EVPB;
    const f4* bevv = (const f4*)(ev + (size_t)batch * NEV + ev0);

    for (int r = t; r < NROWS; r += THREADS) hist[r] = 0u;
    __syncthreads();

    // pass 1: ONE global read (nt, batched x4 for MLP), pack to registers
    unsigned int pkd[EPT];                   // y<<12 | x<<1 | p ; 0xFFFFFFFF = tail
    if (cnt == EVPB) {
#pragma unroll
        for (int h = 0; h < EPT / 4; ++h) {
            f4 vv[4];
#pragma unroll
            for (int k = 0; k < 4; ++k)
                vv[k] = __builtin_nontemporal_load(&bevv[t + (h * 4 + k) * THREADS]);
#pragma unroll
            for (int k = 0; k < 4; ++k) {
                unsigned int yi = (unsigned int)(int)vv[k].z;
                unsigned int xi = (unsigned int)(int)vv[k].y;
                unsigned int pb = (vv[k].w == 1.0f) ? 1u : 0u;
                pkd[h * 4 + k] = (yi << 12) | (xi << 1) | pb;
                atomicAdd(&hist[yi], 1u);
            }
        }
    } else {
#pragma unroll
        for (int k = 0; k < EPT; ++k) {
            int e = t + k * THREADS;
            unsigned int c = 0xFFFFFFFFu;
            if (e < cnt) {
                f4 v = __builtin_nontemporal_load(&bevv[e]);
                unsigned int yi = (unsigned int)(int)v.z;
                unsigned int xi = (unsigned int)(int)v.y;
                unsigned int pb = (v.w == 1.0f) ? 1u : 0u;
                c = (yi << 12) | (xi << 1) | pb;
                atomicAdd(&hist[yi], 1u);
            }
            pkd[k] = c;
        }
    }
    __syncthreads();

    // exclusive prefix over 720 rows: threads 0..179 own 4 rows; shfl scan
    unsigned int own = 0u;
    int b4 = t * 4;
    if (t < 180) own = hist[b4] + hist[b4 + 1] + hist[b4 + 2] + hist[b4 + 3];
    unsigned int incl = own;
    for (int d = 1; d < 64; d <<= 1) {
        unsigned int n = __shfl_up(incl, d);
        if ((t & 63) >= d) incl += n;
    }
    if ((t & 63) == 63) wtot[t >> 6] = incl;   // waves 3..7 contribute 0
    __syncthreads();
    unsigned int wbase = 0u;
    for (int w = 0; w < (t >> 6); ++w) wbase += wtot[w];
    unsigned int total = 0u;
    for (int w = 0; w < 8; ++w) total += wtot[w];        // == cnt
    if (t < 180) {
        unsigned int run = wbase + incl - own;
        offs[b4] = run;          run += hist[b4];
        offs[b4 + 1] = run;      run += hist[b4 + 1];
        offs[b4 + 2] = run;      run += hist[b4 + 2];
        offs[b4 + 3] = run;
    }
    __syncthreads();

    // publish per-block row prefix BEFORE pass 2 mutates offs
    unsigned int* pg = pref_g + (size_t)blockIdx.x * PH;
    for (int r = t; r < PH; r += THREADS)
        pg[r] = (r < NROWS) ? offs[r] : total;
    __syncthreads();

    // pass 2: from REGISTERS, rank, place row-sorted in stage
    if (cnt == EVPB) {
#pragma unroll
        for (int k = 0; k < EPT; ++k) {
            unsigned int c   = pkd[k];
            unsigned int yi  = c >> 12;
            unsigned int xi  = (c >> 1) & 0x7FFu;
            unsigned int e   = (unsigned int)(t + k * THREADS);
            unsigned int pk  = (xi << 20)
                             | (((unsigned int)ev0 + e + 1u) << 1) | (c & 1u);
            unsigned int slot = atomicAdd(&offs[yi], 1u);
            stage[slot] = pk;
        }
    } else {
#pragma unroll
        for (int k = 0; k < EPT; ++k) {
            unsigned int c = pkd[k];
            if (c != 0xFFFFFFFFu) {
                unsigned int yi  = c >> 12;
                unsigned int xi  = (c >> 1) & 0x7FFu;
                unsigned int e   = (unsigned int)(t + k * THREADS);
                unsigned int pk  = (xi << 20)
                                 | (((unsigned int)ev0 + e + 1u) << 1) | (c & 1u);
                unsigned int slot = atomicAdd(&offs[yi], 1u);
                stage[slot] = pk;
            }
        }
    }
    __syncthreads();

    // write the sorted chunk, fully coalesced (keep in L2/L3 for render)
    uint4* dst = (uint4*)(bins + (size_t)blockIdx.x * EVPB);
    const uint4* src = (const uint4*)stage;
    for (int k = t; k < EVPB / 4; k += THREADS)
        dst[k] = src[k];
}

__global__ __launch_bounds__(RTHREADS) void render_k(const unsigned int* __restrict__ pref_g,
                                                     const unsigned int* __restrict__ bins,
                                                     float4* __restrict__ out) {
    __shared__ unsigned int win[WIDTH];      // 5 KB
    __shared__ unsigned int stage[STCAP];    // 4 KB dense staged events
    __shared__ unsigned int segbase[BPB];
    __shared__ unsigned int segpref[65];     // total ~9.5 KB -> 16 blocks/CU

    int t = threadIdx.x;
    int rowid = blockIdx.x;                  // batch*720 + row
    int batch = rowid / NROWS;
    int row   = rowid - batch * NROWS;

    // issue scattered pref loads first; zero win while they fly
    unsigned int p0 = 0u, p1 = 0u;
    if (t < BPB) {
        const unsigned int* pg = pref_g + (size_t)(batch * BPB + t) * PH + row;
        p0 = pg[0]; p1 = pg[1];
    }
    for (int x = t; x < WIDTH; x += RTHREADS) win[x] = 0u;

    unsigned int mycnt = 0u;
    if (t < BPB) {
        segbase[t] = (unsigned int)((batch * BPB + t) * EVPB) + p0;
        mycnt = p1 - p0;
    }
    if (t < 64) {                            // wave-0 inclusive scan of 62 counts
        unsigned int v = mycnt;
        for (int d = 1; d < 64; d <<= 1) {
            unsigned int n = __shfl_up(v, d);
            if (t >= d) v += n;
        }
        if (t == 0) segpref[0] = 0u;
        segpref[t + 1] = v;
    }
    __syncthreads();

    unsigned int total = segpref[BPB];       // ~694
    if (total <= STCAP) {
        // async DMA: wave w stages segments {w, w+2, ...} densely into stage
        int w = t >> 6, lane = t & 63;
        for (int s = w; s < BPB; s += RTHREADS / 64) {
            unsigned int sp = segpref[s];
            unsigned int cn = segpref[s + 1] - sp;
            unsigned int gb = segbase[s];
            for (unsigned int off = 0; off < cn; off += 64u) {
                if ((unsigned int)lane < cn - off) {
                    GU* gsrc = (GU*)(bins + gb + off + (unsigned int)lane);
                    __builtin_amdgcn_global_load_lds(gsrc, (LU*)&stage[sp + off], 4, 0, 0);
                }
            }
        }
        __syncthreads();                     // drains vmcnt (2-wave scope)

        // merge from dense LDS: contiguous ds_reads, no search
        for (unsigned int j = t; j < total; j += RTHREADS) {
            unsigned int pk = stage[j];
            atomicMax(&win[pk >> 20], pk & 0xFFFFFu);
        }
    } else {
        // exact fallback (P ~ 1e-30, block-uniform): binary-search gather
        for (unsigned int j = t; j < total; j += RTHREADS) {
            int lo = 0, hi = BPB - 1;
            while (lo < hi) {
                int mid = (lo + hi + 1) >> 1;
                if (segpref[mid] <= j) lo = mid; else hi = mid - 1;
            }
            unsigned int pk = bins[segbase[lo] + (j - segpref[lo])];
            atomicMax(&win[pk >> 20], pk & 0xFFFFFu);
        }
    }
    __syncthreads();

    // write one image row: 1280 px * 3 ch = 960 float4; one float4 per
    // thread per iteration (lane-contiguous per store instruction)
    f4* orow = (f4*)out + (size_t)rowid * (WIDTH * 3 / 4);
    for (int j = t; j < WIDTH * 3 / 4; j += RTHREADS) {
        float vals[4];
#pragma unroll
        for (int c = 0; c < 4; ++c) {
            int fi = j * 4 + c;
            int px = fi / 3;
            int ch = fi - px * 3;
            unsigned int k = win[px];
            float val;
            if (k == 0u) val = (ch == 2) ? 510.0f : 255.0f;
            else if (ch == 2) val = 255.0f;
            else if (ch == 0) val = (k & 1u) ? 0.0f : 255.0f;
            else              val = (k & 1u) ? 255.0f : 0.0f;
            vals[c] = val;
        }
        f4 o = { vals[0], vals[1], vals[2], vals[3] };
        __builtin_nontemporal_store(o, orow + j);
    }
}

extern "C" void kernel_launch(void* const* d_in, const int* in_sizes, int n_in,
                              void* d_out, int out_size, void* d_ws, size_t ws_size,
                              hipStream_t stream) {
    const float4* ev = (const float4*)d_in[0];
    unsigned int* pref_g = (unsigned int*)d_ws;
    unsigned int* bins   = (unsigned int*)((char*)d_ws + 0x400000);
    float4* out = (float4*)d_out;

    scatter_k<<<NBLK, THREADS, 0, stream>>>(ev, pref_g, bins);
    render_k<<<BATCH * NROWS, RTHREADS, 0, stream>>>(pref_g, bins, out);
}

// Round 25
// 79.905 us; speedup vs baseline: 1.1152x; 1.1152x over previous
//
#include <hip/hip_runtime.h>

// Event-to-image: B=16, N=500000 events (t,x,y,p) f32 -> (16,720,1280,3) f32.
// Last-event-wins per pixel: p==1 -> (0,255,255); p==0 -> (255,0,255);
// untouched -> (255,255,510). Order-independent via max over
// key = ((event_idx+1)<<1)|p (20 bits), pk = pos<<20 | key,
// pos = (y&1)*1280 + x (12 bits) -- 2-row bands.
//
// FINAL = R22 (79.97us, best of 24 rounds; reverted from R24's cooperative
// fusion, which failed co-residency and never launched).
// Structure: scatter (512 thr, 32 waves/CU, one nt global read batched x4,
// register-cached packed events, LDS counting-sort by 2-row band, coalesced
// chunk write) + render (256 thr per band, async global_load_lds DMA gather
// into dense LDS, LDS atomicMax merge, interleaved nt float4 stores).
// Probe ledger: scatter occupancy/reg-cache/MLP all captured; 8 render
// axes probed null at 80+-3; traffic floor ~55us, achieved ~80us.

#define WIDTH   1280
#define HEIGHT  720
#define BATCH   16
#define NEV     500000
#define THREADS 512                         // scatter block
#define EPT     16
#define EVPB    (THREADS * EPT)             // 8192 events per block
#define BPB     ((NEV + EVPB - 1) / EVPB)   // 62 blocks per batch
#define NBLK    (BATCH * BPB)               // 992
#define NBANDS  360                         // 2-row bands per batch
#define PH      (NBANDS + 1)                // 361 prefix entries per block
#define RTHREADS 256                        // render block
#define STCAP   1792                        // staged events cap (10.8 sigma)

typedef float f4 __attribute__((ext_vector_type(4)));
typedef const __attribute__((address_space(1))) unsigned int GU;
typedef __attribute__((address_space(3))) unsigned int LU;

// ws layout: [0, NBLK*PH*4)=pref_g (1.43 MB); [0x400000, +NBLK*EVPB*4)=bins (32.5 MB)

__global__ __launch_bounds__(THREADS, 8) void scatter_k(const float4* __restrict__ ev,
                                                        unsigned int* __restrict__ pref_g,
                                                        unsigned int* __restrict__ bins) {
    __shared__ unsigned int hist[NBANDS];
    __shared__ unsigned int offs[NBANDS];
    __shared__ unsigned int wtot[8];
    __shared__ unsigned int stage[EVPB];     // 32 KB (total ~34.9 KB -> 4 blocks/CU)

    int t = threadIdx.x;
    int batch = blockIdx.x / BPB;
    int blk   = blockIdx.x % BPB;
    int ev0   = blk * EVPB;
    int cnt   = NEV - ev0; if (cnt > EVPB) cnt = EVPB;
    const f4* bevv = (const f4*)(ev + (size_t)batch * NEV + ev0);

    if (t < NBANDS) hist[t] = 0u;
    __syncthreads();

    // pass 1: ONE global read (nt), pack to registers, histogram
    unsigned int pkd[EPT];                   // y<<12 | x<<1 | p ; 0xFFFFFFFF = tail
    if (cnt == EVPB) {
#pragma unroll
        for (int h = 0; h < EPT / 4; ++h) {
            f4 vv[4];
#pragma unroll
            for (int k = 0; k < 4; ++k)
                vv[k] = __builtin_nontemporal_load(&bevv[t + (h * 4 + k) * THREADS]);
#pragma unroll
            for (int k = 0; k < 4; ++k) {
                unsigned int yi = (unsigned int)(int)vv[k].z;
                unsigned int xi = (unsigned int)(int)vv[k].y;
                unsigned int pb = (vv[k].w == 1.0f) ? 1u : 0u;
                pkd[h * 4 + k] = (yi << 12) | (xi << 1) | pb;
                atomicAdd(&hist[yi >> 1], 1u);
            }
        }
    } else {
#pragma unroll
        for (int k = 0; k < EPT; ++k) {
            int e = t + k * THREADS;
            unsigned int c = 0xFFFFFFFFu;
            if (e < cnt) {
                f4 v = __builtin_nontemporal_load(&bevv[e]);
                unsigned int yi = (unsigned int)(int)v.z;
                unsigned int xi = (unsigned int)(int)v.y;
                unsigned int pb = (v.w == 1.0f) ? 1u : 0u;
                c = (yi << 12) | (xi << 1) | pb;
                atomicAdd(&hist[yi >> 1], 1u);
            }
            pkd[k] = c;
        }
    }
    __syncthreads();

    // exclusive prefix over 360 bands: threads 0..89 own 4 bands; shfl scan
    unsigned int own = 0u;
    int b4 = t * 4;
    if (t < 90) own = hist[b4] + hist[b4 + 1] + hist[b4 + 2] + hist[b4 + 3];
    unsigned int incl = own;
    for (int d = 1; d < 64; d <<= 1) {
        unsigned int n = __shfl_up(incl, d);
        if ((t & 63) >= d) incl += n;
    }
    if ((t & 63) == 63) wtot[t >> 6] = incl;   // waves 2..7 contribute 0
    __syncthreads();
    unsigned int wbase = 0u;
    for (int w = 0; w < (t >> 6); ++w) wbase += wtot[w];
    unsigned int total = 0u;
    for (int w = 0; w < 8; ++w) total += wtot[w];        // == cnt
    if (t < 90) {
        unsigned int run = wbase + incl - own;
        offs[b4] = run;          run += hist[b4];
        offs[b4 + 1] = run;      run += hist[b4 + 1];
        offs[b4 + 2] = run;      run += hist[b4 + 2];
        offs[b4 + 3] = run;
    }
    __syncthreads();

    // publish per-block band prefix BEFORE pass 2 mutates offs
    unsigned int* pg = pref_g + (size_t)blockIdx.x * PH;
    if (t < PH) pg[t] = (t < NBANDS) ? offs[t] : total;
    __syncthreads();

    // pass 2: from REGISTERS, rank, place sorted in stage
    if (cnt == EVPB) {
#pragma unroll
        for (int k = 0; k < EPT; ++k) {
            unsigned int c   = pkd[k];
            unsigned int yi  = c >> 12;
            unsigned int xi  = (c >> 1) & 0x7FFu;
            unsigned int pos = (yi & 1u) * 1280u + xi;
            unsigned int e   = (unsigned int)(t + k * THREADS);
            unsigned int pk  = (pos << 20)
                             | (((unsigned int)ev0 + e + 1u) << 1) | (c & 1u);
            unsigned int slot = atomicAdd(&offs[yi >> 1], 1u);
            stage[slot] = pk;
        }
    } else {
#pragma unroll
        for (int k = 0; k < EPT; ++k) {
            unsigned int c = pkd[k];
            if (c != 0xFFFFFFFFu) {
                unsigned int yi  = c >> 12;
                unsigned int xi  = (c >> 1) & 0x7FFu;
                unsigned int pos = (yi & 1u) * 1280u + xi;
                unsigned int e   = (unsigned int)(t + k * THREADS);
                unsigned int pk  = (pos << 20)
                                 | (((unsigned int)ev0 + e + 1u) << 1) | (c & 1u);
                unsigned int slot = atomicAdd(&offs[yi >> 1], 1u);
                stage[slot] = pk;
            }
        }
    }
    __syncthreads();

    // write the sorted chunk, fully coalesced (keep in L2/L3 for render)
    uint4* dst = (uint4*)(bins + (size_t)blockIdx.x * EVPB);
    const uint4* src = (const uint4*)stage;
    for (int k = t; k < EVPB / 4; k += THREADS)
        dst[k] = src[k];
}

__global__ __launch_bounds__(RTHREADS) void render_k(const unsigned int* __restrict__ pref_g,
                                                     const unsigned int* __restrict__ bins,
                                                     float4* __restrict__ out) {
    __shared__ unsigned int win[2 * WIDTH];  // 10 KB
    __shared__ unsigned int stage[STCAP];    // 7 KB dense staged events
    __shared__ unsigned int segbase[BPB];
    __shared__ unsigned int segpref[65];

    int t = threadIdx.x;
    int bandid = blockIdx.x;                 // batch*360 + band
    int batch = bandid / NBANDS;
    int band  = bandid - batch * NBANDS;

    // issue scattered pref loads first; zero win while they fly
    unsigned int p0 = 0u, p1 = 0u;
    if (t < BPB) {
        const unsigned int* pg = pref_g + (size_t)(batch * BPB + t) * PH + band;
        p0 = pg[0]; p1 = pg[1];
    }
    for (int x = t; x < 2 * WIDTH; x += RTHREADS) win[x] = 0u;

    unsigned int mycnt = 0u;
    if (t < BPB) {
        segbase[t] = (unsigned int)((batch * BPB + t) * EVPB) + p0;
        mycnt = p1 - p0;
    }
    if (t < 64) {                            // wave-0 inclusive scan of 62 counts
        unsigned int v = mycnt;
        for (int d = 1; d < 64; d <<= 1) {
            unsigned int n = __shfl_up(v, d);
            if (t >= d) v += n;
        }
        if (t == 0) segpref[0] = 0u;
        segpref[t + 1] = v;
    }
    __syncthreads();

    unsigned int total = segpref[BPB];       // ~1389
    if (total <= STCAP) {
        // async DMA: wave w stages segments {w, w+4, ...} densely into stage
        int w = t >> 6, lane = t & 63;
        for (int s = w; s < BPB; s += RTHREADS / 64) {
            unsigned int sp = segpref[s];
            unsigned int cn = segpref[s + 1] - sp;
            unsigned int gb = segbase[s];
            for (unsigned int off = 0; off < cn; off += 64u) {
                if ((unsigned int)lane < cn - off) {
                    GU* gsrc = (GU*)(bins + gb + off + (unsigned int)lane);
                    __builtin_amdgcn_global_load_lds(gsrc, (LU*)&stage[sp + off], 4, 0, 0);
                }
            }
        }
        __syncthreads();                     // compiler drains vmcnt before barrier

        // merge from dense LDS: contiguous ds_reads, no search
        for (unsigned int j = t; j < total; j += RTHREADS) {
            unsigned int pk = stage[j];
            atomicMax(&win[pk >> 20], pk & 0xFFFFFu);
        }
    } else {
        // exact fallback (P ~ 1e-26, block-uniform): binary-search gather
        for (unsigned int j = t; j < total; j += RTHREADS) {
            int lo = 0, hi = BPB - 1;
            while (lo < hi) {
                int mid = (lo + hi + 1) >> 1;
                if (segpref[mid] <= j) lo = mid; else hi = mid - 1;
            }
            unsigned int pk = bins[segbase[lo] + (j - segpref[lo])];
            atomicMax(&win[pk >> 20], pk & 0xFFFFFu);
        }
    }
    __syncthreads();

    // write two image rows: 1920 float4, one per thread per iteration
    // (lane-contiguous 1024B per store instruction)
    f4* orow = (f4*)out + (size_t)bandid * (2 * WIDTH * 3 / 4);
    for (int j = t; j < 2 * WIDTH * 3 / 4; j += RTHREADS) {
        float vals[4];
#pragma unroll
        for (int c = 0; c < 4; ++c) {
            int fi = j * 4 + c;
            int px = fi / 3;
            int ch = fi - px * 3;
            unsigned int k = win[px];
            float val;
            if (k == 0u) val = (ch == 2) ? 510.0f : 255.0f;
            else if (ch == 2) val = 255.0f;
            else if (ch == 0) val = (k & 1u) ? 0.0f : 255.0f;
            else              val = (k & 1u) ? 255.0f : 0.0f;
            vals[c] = val;
        }
        f4 o = { vals[0], vals[1], vals[2], vals[3] };
        __builtin_nontemporal_store(o, orow + j);
    }
}

extern "C" void kernel_launch(void* const* d_in, const int* in_sizes, int n_in,
                              void* d_out, int out_size, void* d_ws, size_t ws_size,
                              hipStream_t stream) {
    const float4* ev = (const float4*)d_in[0];
    unsigned int* pref_g = (unsigned int*)d_ws;
    unsigned int* bins   = (unsigned int*)((char*)d_ws + 0x400000);
    float4* out = (float4*)d_out;

    scatter_k<<<NBLK, THREADS, 0, stream>>>(ev, pref_g, bins);
    render_k<<<BATCH * NBANDS, RTHREADS, 0, stream>>>(pref_g, bins, out);
}